// Round 1
// baseline (452.544 us; speedup 1.0000x reference)
//
#include <hip/hip_runtime.h>
#include <hip/hip_bf16.h>
#include <math.h>

#define N_  8
#define C_  528
#define T_  16
#define H_  32
#define W_  32
#define HW_ 1024
#define R_  1024
#define OUT_ 8
#define SR_ 2
#define SCALE_ (1.0f/16.0f)

// ---------------------------------------------------------------------------
// Kernel 1: feat_t[n][p][c] = mean_t x[n][c][t][p], NCHW -> N(HW)C transpose.
// Tile: 64 channels x 64 pixels, through LDS (pad 65 -> conflict-free).
// grid = (16 p-tiles, 9 c-tiles, 8 n), block = 256.
// ---------------------------------------------------------------------------
__global__ __launch_bounds__(256) void mean_transpose(
    const float* __restrict__ x, float* __restrict__ feat_t) {
  const int p0 = blockIdx.x * 64;
  const int c0 = blockIdx.y * 64;
  const int n  = blockIdx.z;

  __shared__ float tile[64][65];   // [p_local][c_local]

  const int tid = threadIdx.x;
  const int p4  = (tid & 15) * 4;  // p_local base (float4 along p)
  const int clo = tid >> 4;        // 0..15

  const float inv_t = 1.0f / 16.0f;
  #pragma unroll
  for (int k = 0; k < 4; ++k) {
    const int c_local = clo + 16 * k;
    const int c = c0 + c_local;
    float4 acc = make_float4(0.f, 0.f, 0.f, 0.f);
    if (c < C_) {
      const float* src = x + ((size_t)(n * C_ + c) * T_) * HW_ + p0 + p4;
      #pragma unroll
      for (int t = 0; t < T_; ++t) {
        const float4 v = *(const float4*)(src + t * HW_);
        acc.x += v.x; acc.y += v.y; acc.z += v.z; acc.w += v.w;
      }
    }
    tile[p4 + 0][c_local] = acc.x * inv_t;
    tile[p4 + 1][c_local] = acc.y * inv_t;
    tile[p4 + 2][c_local] = acc.z * inv_t;
    tile[p4 + 3][c_local] = acc.w * inv_t;
  }
  __syncthreads();

  const int c_out  = tid & 63;
  const int p_base = (tid >> 6) * 16;  // 0,16,32,48
  if (c0 + c_out < C_) {
    #pragma unroll
    for (int k = 0; k < 16; ++k) {
      const int p_out = p_base + k;
      feat_t[((size_t)n * HW_ + p0 + p_out) * C_ + c0 + c_out] =
          tile[p_out][c_out];
    }
  }
}

// ---------------------------------------------------------------------------
// Kernel 2: per-roi separable ROI-align + spatial mean + 3-layer MLP.
// grid = 1024 (one block per roi), block = 256.
// ---------------------------------------------------------------------------
__global__ __launch_bounds__(256) void roi_mlp(
    const float* __restrict__ feat_t, const float* __restrict__ bbox,
    const float* __restrict__ W1, const float* __restrict__ b1,
    const float* __restrict__ W2, const float* __restrict__ b2,
    const float* __restrict__ W3, const float* __restrict__ b3,
    float* __restrict__ out) {
  const int r = blockIdx.x;
  const int tid = threadIdx.x;

  __shared__ float sAy[32], sAx[32];
  __shared__ float pooled[C_];
  __shared__ float h1[128];
  __shared__ float h2[32];
  __shared__ int   sbounds[5];  // ylo,yhi,xlo,xhi,bidx

  // zero the weight accumulators
  if (tid < 32) { sAy[tid] = 0.f; sAx[tid] = 0.f; }
  __syncthreads();

  // --- Phase A: per-axis separable weights -------------------------------
  const float bv  = bbox[r * 5 + 0];
  const float x1v = bbox[r * 5 + 1];
  const float y1v = bbox[r * 5 + 2];
  const float x2v = bbox[r * 5 + 3];
  const float y2v = bbox[r * 5 + 4];

  if (tid < 32) {
    const bool is_y = (tid < 16);
    const int  i    = tid & 15;
    const float s1  = (is_y ? y1v : x1v) * SCALE_ - 0.5f;
    const float s2  = (is_y ? y2v : x2v) * SCALE_ - 0.5f;
    const float bin = (s2 - s1) * (1.0f / OUT_);
    const float v   = s1 + ((float)i + 0.5f) * (bin * 0.5f);
    const bool valid = (v >= -1.0f) && (v <= (float)H_);
    if (valid) {
      float vc = fminf(fmaxf(v, 0.0f), (float)(H_ - 1));
      float lo_f = floorf(vc);
      float fr = vc - lo_f;
      int lo = (int)lo_f;
      int hi = min(lo + 1, H_ - 1);
      float* A = is_y ? sAy : sAx;
      atomicAdd(&A[lo], 1.0f - fr);
      atomicAdd(&A[hi], fr);
    }
  }
  __syncthreads();

  // --- bounds of nonzero support (support is contiguous) -----------------
  if (tid == 0) {
    int lo = 32, hi = -1;
    for (int i = 0; i < 32; ++i)
      if (sAy[i] != 0.f) { if (lo == 32) lo = i; hi = i; }
    sbounds[0] = lo; sbounds[1] = hi;
    sbounds[4] = (int)bv;
  } else if (tid == 64) {
    int lo = 32, hi = -1;
    for (int i = 0; i < 32; ++i)
      if (sAx[i] != 0.f) { if (lo == 32) lo = i; hi = i; }
    sbounds[2] = lo; sbounds[3] = hi;
  }
  __syncthreads();

  const int ylo = sbounds[0], yhi = sbounds[1];
  const int xlo = sbounds[2], xhi = sbounds[3];
  const int bidx = sbounds[4];

  // --- Phase B: gather-reduce pooled[c] ----------------------------------
  const float inv_cnt = 1.0f / (float)(OUT_ * SR_ * OUT_ * SR_);  // 1/256
  const float* fb = feat_t + (size_t)bidx * HW_ * C_;
  for (int c = tid; c < C_; c += 256) {
    float acc = 0.f;
    for (int Y = ylo; Y <= yhi; ++Y) {
      const float wy = sAy[Y];
      const float* rowp = fb + (size_t)(Y * W_) * C_ + c;
      float rsum = 0.f;
      for (int X = xlo; X <= xhi; ++X) {
        rsum += sAx[X] * rowp[(size_t)X * C_];
      }
      acc += wy * rsum;
    }
    pooled[c] = acc * inv_cnt;
  }
  __syncthreads();

  // --- Phase C: MLP layer 1 (528 -> 128, relu) ---------------------------
  if (tid < 128) {
    float acc = b1[tid];
    for (int c = 0; c < C_; ++c) {
      acc += pooled[c] * W1[c * 128 + tid];
    }
    h1[tid] = fmaxf(acc, 0.0f);
  }
  __syncthreads();

  // --- layer 2 (128 -> 32, no activation) --------------------------------
  if (tid < 32) {
    float acc = b2[tid];
    #pragma unroll 4
    for (int j = 0; j < 128; ++j) {
      acc += h1[j] * W2[j * 32 + tid];
    }
    h2[tid] = acc;
  }
  __syncthreads();

  // --- layer 3 (32 -> 1) + sigmoid ---------------------------------------
  if (tid == 0) {
    float acc = b3[0];
    #pragma unroll
    for (int k = 0; k < 32; ++k) acc += h2[k] * W3[k];
    out[r] = 1.0f / (1.0f + expf(-acc));
  }
}

extern "C" void kernel_launch(void* const* d_in, const int* in_sizes, int n_in,
                              void* d_out, int out_size, void* d_ws, size_t ws_size,
                              hipStream_t stream) {
  const float* x    = (const float*)d_in[0];
  const float* bbox = (const float*)d_in[1];
  const float* W1   = (const float*)d_in[2];
  const float* b1   = (const float*)d_in[3];
  const float* W2   = (const float*)d_in[4];
  const float* b2   = (const float*)d_in[5];
  const float* W3   = (const float*)d_in[6];
  const float* b3   = (const float*)d_in[7];
  float* out = (float*)d_out;

  float* feat_t = (float*)d_ws;  // 8*1024*528 floats = 17.3 MB

  mean_transpose<<<dim3(16, 9, 8), 256, 0, stream>>>(x, feat_t);
  roi_mlp<<<R_, 256, 0, stream>>>(feat_t, bbox, W1, b1, W2, b2, W3, b3, out);
}

// Round 2
// 427.644 us; speedup vs baseline: 1.0582x; 1.0582x over previous
//
#include <hip/hip_runtime.h>
#include <hip/hip_bf16.h>
#include <math.h>

#define N_  8
#define C_  528
#define T_  16
#define H_  32
#define W_  32
#define HW_ 1024
#define R_  1024
#define OUT_ 8
#define SR_ 2
#define SCALE_ (1.0f/16.0f)

// ---------------------------------------------------------------------------
// Kernel 1: feat_t[n][p][c] = mean_t x[n][c][t][p], NCHW -> N(HW)C transpose.
// Tile: 64 channels x 64 pixels through LDS (pad to 68 -> float4-aligned
// rows, conflict-acceptable). grid = (16 p-tiles, 9 c-tiles, 8 n), block=256.
// ---------------------------------------------------------------------------
__global__ __launch_bounds__(256) void mean_transpose(
    const float* __restrict__ x, float* __restrict__ feat_t) {
  const int p0 = blockIdx.x * 64;
  const int c0 = blockIdx.y * 64;
  const int n  = blockIdx.z;

  __shared__ float tile[64][68];   // [p_local][c_local], row = 272B (16B mult)

  const int tid = threadIdx.x;
  const int p4  = (tid & 15) * 4;  // p_local base (float4 along p)
  const int clo = tid >> 4;        // 0..15

  const float inv_t = 1.0f / 16.0f;
  #pragma unroll
  for (int k = 0; k < 4; ++k) {
    const int c_local = clo + 16 * k;
    const int c = c0 + c_local;
    float4 acc = make_float4(0.f, 0.f, 0.f, 0.f);
    if (c < C_) {
      const float* src = x + ((size_t)(n * C_ + c) * T_) * HW_ + p0 + p4;
      #pragma unroll
      for (int t = 0; t < T_; ++t) {
        const float4 v = *(const float4*)(src + t * HW_);
        acc.x += v.x; acc.y += v.y; acc.z += v.z; acc.w += v.w;
      }
    }
    tile[p4 + 0][c_local] = acc.x * inv_t;
    tile[p4 + 1][c_local] = acc.y * inv_t;
    tile[p4 + 2][c_local] = acc.z * inv_t;
    tile[p4 + 3][c_local] = acc.w * inv_t;
  }
  __syncthreads();

  // store side: float4 over channels. 16 c-chunks x 16 p per pass, 4 passes.
  const int c4 = (tid & 15) * 4;
  const int p  = tid >> 4;
  if (c0 + c4 < C_) {
    #pragma unroll
    for (int k = 0; k < 4; ++k) {
      const int p_out = p + 16 * k;
      const float4 v = *(const float4*)&tile[p_out][c4];
      *(float4*)&feat_t[((size_t)n * HW_ + p0 + p_out) * C_ + c0 + c4] = v;
    }
  }
}

// ---------------------------------------------------------------------------
// Kernel 2: per-roi separable ROI-align + spatial mean + 3-layer MLP.
// grid = 1024 (one block per roi), block = 256.
// ---------------------------------------------------------------------------
__global__ __launch_bounds__(256) void roi_mlp(
    const float* __restrict__ feat_t, const float* __restrict__ bbox,
    const float* __restrict__ W1, const float* __restrict__ b1,
    const float* __restrict__ W2, const float* __restrict__ b2,
    const float* __restrict__ W3, const float* __restrict__ b3,
    float* __restrict__ out) {
  const int r = blockIdx.x;
  const int tid = threadIdx.x;

  __shared__ float sAy[32], sAx[32];
  __shared__ float pooled[C_];
  __shared__ float h1p[2][128];
  __shared__ float h1[128];
  __shared__ float p2[8][32];
  __shared__ float h2[32];
  __shared__ int   sbounds[5];  // ylo,yhi,xlo,xhi,bidx

  if (tid < 32) { sAy[tid] = 0.f; sAx[tid] = 0.f; }
  __syncthreads();

  // --- Phase A: per-axis separable weights + bounds (wave0, lanes 0-31) ---
  if (tid < 32) {
    const bool is_y = (tid < 16);
    const int  i    = tid & 15;
    const float s1  = bbox[r * 5 + (is_y ? 2 : 1)] * SCALE_ - 0.5f;
    const float s2  = bbox[r * 5 + (is_y ? 4 : 3)] * SCALE_ - 0.5f;
    const float bin = (s2 - s1) * (1.0f / OUT_);
    const float v   = s1 + ((float)i + 0.5f) * (bin * 0.5f);
    const bool valid = (v >= -1.0f) && (v <= (float)H_);
    int lo = 999, hi = -1;
    if (valid) {
      float vc = fminf(fmaxf(v, 0.0f), (float)(H_ - 1));
      float lo_f = floorf(vc);
      float fr = vc - lo_f;
      lo = (int)lo_f;
      hi = min(lo + 1, H_ - 1);
      float* A = is_y ? sAy : sAx;
      atomicAdd(&A[lo], 1.0f - fr);
      atomicAdd(&A[hi], fr);
    }
    // min/max reduce within each 16-lane half of wave 0
    int mn = lo, mx = hi;
    #pragma unroll
    for (int m = 8; m >= 1; m >>= 1) {
      mn = min(mn, __shfl_xor(mn, m, 16));
      mx = max(mx, __shfl_xor(mx, m, 16));
    }
    if (tid == 0)  { sbounds[0] = mn; sbounds[1] = mx;
                     sbounds[4] = (int)bbox[r * 5]; }
    if (tid == 16) { sbounds[2] = mn; sbounds[3] = mx; }
  }
  __syncthreads();

  const int ylo = sbounds[0], yhi = sbounds[1];
  const int xlo = sbounds[2], xhi = sbounds[3];
  const int bidx = sbounds[4];

  // --- Phase B: gather-reduce pooled[c], float4 over channels -------------
  const float inv_cnt = 1.0f / 256.0f;
  if (tid < 132) {
    const float* fb = feat_t + (size_t)bidx * HW_ * C_ + tid * 4;
    float4 acc = make_float4(0.f, 0.f, 0.f, 0.f);
    for (int Y = ylo; Y <= yhi; ++Y) {
      const float wy = sAy[Y];
      const float* rp = fb + (size_t)(Y * W_) * C_;
      float4 rs = make_float4(0.f, 0.f, 0.f, 0.f);
      for (int X = xlo; X <= xhi; ++X) {
        const float4 v = *(const float4*)(rp + (size_t)X * C_);
        const float wx = sAx[X];
        rs.x += wx * v.x; rs.y += wx * v.y; rs.z += wx * v.z; rs.w += wx * v.w;
      }
      acc.x += wy * rs.x; acc.y += wy * rs.y; acc.z += wy * rs.z; acc.w += wy * rs.w;
    }
    acc.x *= inv_cnt; acc.y *= inv_cnt; acc.z *= inv_cnt; acc.w *= inv_cnt;
    *(float4*)&pooled[tid * 4] = acc;
  }
  __syncthreads();

  // --- Layer 1 (528 -> 128, relu): 2 half-K partials x 128 outputs --------
  {
    const int j = tid & 127;
    const int half = tid >> 7;
    const int cb = half * 264;
    float acc = 0.f;
    const float* w = W1 + j;
    #pragma unroll 4
    for (int c = cb; c < cb + 264; ++c) {
      acc += pooled[c] * w[(size_t)c * 128];
    }
    h1p[half][j] = acc;
  }
  __syncthreads();
  if (tid < 128) h1[tid] = fmaxf(h1p[0][tid] + h1p[1][tid] + b1[tid], 0.f);
  __syncthreads();

  // --- Layer 2 (128 -> 32): 8 partials x 32 outputs -----------------------
  {
    const int j = tid & 31;
    const int part = tid >> 5;
    float acc = 0.f;
    #pragma unroll
    for (int k = part * 16; k < part * 16 + 16; ++k) {
      acc += h1[k] * W2[k * 32 + j];
    }
    p2[part][j] = acc;
  }
  __syncthreads();
  if (tid < 32) {
    float acc = b2[tid];
    #pragma unroll
    for (int p = 0; p < 8; ++p) acc += p2[p][tid];
    h2[tid] = acc;
  }
  __syncthreads();

  // --- Layer 3 (32 -> 1) + sigmoid, wave reduce ---------------------------
  if (tid < 64) {
    float t = (tid < 32) ? h2[tid] * W3[tid] : 0.f;
    #pragma unroll
    for (int off = 16; off >= 1; off >>= 1) t += __shfl_down(t, off);
    if (tid == 0) out[r] = 1.0f / (1.0f + expf(-(t + b3[0])));
  }
}

extern "C" void kernel_launch(void* const* d_in, const int* in_sizes, int n_in,
                              void* d_out, int out_size, void* d_ws, size_t ws_size,
                              hipStream_t stream) {
  const float* x    = (const float*)d_in[0];
  const float* bbox = (const float*)d_in[1];
  const float* W1   = (const float*)d_in[2];
  const float* b1   = (const float*)d_in[3];
  const float* W2   = (const float*)d_in[4];
  const float* b2   = (const float*)d_in[5];
  const float* W3   = (const float*)d_in[6];
  const float* b3   = (const float*)d_in[7];
  float* out = (float*)d_out;

  float* feat_t = (float*)d_ws;  // 8*1024*528 floats = 17.3 MB

  mean_transpose<<<dim3(16, 9, 8), 256, 0, stream>>>(x, feat_t);
  roi_mlp<<<R_, 256, 0, stream>>>(feat_t, bbox, W1, b1, W2, b2, W3, b3, out);
}

// Round 3
// 414.463 us; speedup vs baseline: 1.0919x; 1.0318x over previous
//
#include <hip/hip_runtime.h>
#include <hip/hip_bf16.h>
#include <math.h>

#define N_  8
#define C_  528
#define T_  16
#define H_  32
#define W_  32
#define HW_ 1024
#define R_  1024
#define OUT_ 8
#define SR_ 2
#define SCALE_ (1.0f/16.0f)
#define YMAX_ 10   // max bilinear row-support: box extent <=6.8 px -> <=8 rows

// ---------------------------------------------------------------------------
// Kernel 1: feat_t[n][p][c] = mean_t x[n][c][t][p], NCHW -> N(HW)C transpose.
// ---------------------------------------------------------------------------
__global__ __launch_bounds__(256) void mean_transpose(
    const float* __restrict__ x, float* __restrict__ feat_t) {
  const int p0 = blockIdx.x * 64;
  const int c0 = blockIdx.y * 64;
  const int n  = blockIdx.z;

  __shared__ float tile[64][68];   // [p_local][c_local], row = 272B

  const int tid = threadIdx.x;
  const int p4  = (tid & 15) * 4;
  const int clo = tid >> 4;

  const float inv_t = 1.0f / 16.0f;
  #pragma unroll
  for (int k = 0; k < 4; ++k) {
    const int c_local = clo + 16 * k;
    const int c = c0 + c_local;
    float4 acc = make_float4(0.f, 0.f, 0.f, 0.f);
    if (c < C_) {
      const float* src = x + ((size_t)(n * C_ + c) * T_) * HW_ + p0 + p4;
      #pragma unroll
      for (int t = 0; t < T_; ++t) {
        const float4 v = *(const float4*)(src + t * HW_);
        acc.x += v.x; acc.y += v.y; acc.z += v.z; acc.w += v.w;
      }
    }
    tile[p4 + 0][c_local] = acc.x * inv_t;
    tile[p4 + 1][c_local] = acc.y * inv_t;
    tile[p4 + 2][c_local] = acc.z * inv_t;
    tile[p4 + 3][c_local] = acc.w * inv_t;
  }
  __syncthreads();

  const int c4 = (tid & 15) * 4;
  const int p  = tid >> 4;
  if (c0 + c4 < C_) {
    #pragma unroll
    for (int k = 0; k < 4; ++k) {
      const int p_out = p + 16 * k;
      const float4 v = *(const float4*)&tile[p_out][c4];
      *(float4*)&feat_t[((size_t)n * HW_ + p0 + p_out) * C_ + c0 + c4] = v;
    }
  }
}

// ---------------------------------------------------------------------------
// Kernel 2: per-roi separable ROI-align + spatial mean + 3-layer MLP.
// grid = 1024 (one block per roi), block = 256.
// ---------------------------------------------------------------------------
__global__ __launch_bounds__(256) void roi_mlp(
    const float* __restrict__ feat_t, const float* __restrict__ bbox,
    const float* __restrict__ W1, const float* __restrict__ b1,
    const float* __restrict__ W2, const float* __restrict__ b2,
    const float* __restrict__ W3, const float* __restrict__ b3,
    float* __restrict__ out) {
  const int r = blockIdx.x;
  const int tid = threadIdx.x;

  __shared__ float sAy[32], sAx[32];
  __shared__ __align__(16) float pooledP[YMAX_][C_];  // per-Y partials
  __shared__ __align__(16) float pooled[C_];
  __shared__ float h1p[2][128];
  __shared__ float h1[128];
  __shared__ float p2[8][32];
  __shared__ float h2[32];
  __shared__ int   sbounds[5];  // ylo,yhi,xlo,xhi,bidx

  if (tid < 32) { sAy[tid] = 0.f; sAx[tid] = 0.f; }
  __syncthreads();

  // --- Phase A: per-axis separable weights + support bounds (lanes 0-31) --
  if (tid < 32) {
    const bool is_y = (tid < 16);
    const int  i    = tid & 15;
    const float s1  = bbox[r * 5 + (is_y ? 2 : 1)] * SCALE_ - 0.5f;
    const float s2  = bbox[r * 5 + (is_y ? 4 : 3)] * SCALE_ - 0.5f;
    const float bin = (s2 - s1) * (1.0f / OUT_);
    const float v   = s1 + ((float)i + 0.5f) * (bin * 0.5f);
    const bool valid = (v >= -1.0f) && (v <= (float)H_);
    int lo = 999, hi = -1;
    if (valid) {
      float vc = fminf(fmaxf(v, 0.0f), (float)(H_ - 1));
      float lo_f = floorf(vc);
      float fr = vc - lo_f;
      lo = (int)lo_f;
      hi = min(lo + 1, H_ - 1);
      float* A = is_y ? sAy : sAx;
      atomicAdd(&A[lo], 1.0f - fr);
      atomicAdd(&A[hi], fr);
    }
    int mn = lo, mx = hi;
    #pragma unroll
    for (int m = 8; m >= 1; m >>= 1) {
      mn = min(mn, __shfl_xor(mn, m, 16));
      mx = max(mx, __shfl_xor(mx, m, 16));
    }
    if (tid == 0)  { sbounds[0] = mn; sbounds[1] = mx;
                     sbounds[4] = (int)bbox[r * 5]; }
    if (tid == 16) { sbounds[2] = mn; sbounds[3] = mx; }
  }
  __syncthreads();

  const int ylo = sbounds[0], yhi = sbounds[1];
  const int xlo = sbounds[2], xhi = sbounds[3];
  const int bidx = sbounds[4];
  const int ny = yhi - ylo + 1;
  const int nx = xhi - xlo + 1;

  // --- Phase B: gather, parallel over (Y-row, channel-quad) tasks ---------
  {
    const float* fb = feat_t + (size_t)bidx * HW_ * C_;
    const int ntask = ny * 132;
    for (int t = tid; t < ntask; t += 256) {
      const int yk = t / 132;          // magic-mul div by const
      const int c4 = t - yk * 132;
      const float wy = sAy[ylo + yk];
      const float* rp = fb + (size_t)((ylo + yk) * W_ + xlo) * C_ + c4 * 4;
      float4 rs = make_float4(0.f, 0.f, 0.f, 0.f);
      for (int xk = 0; xk < nx; ++xk) {
        const float wx = sAx[xlo + xk];
        const float4 v = *(const float4*)(rp + (size_t)xk * C_);
        rs.x += wx * v.x; rs.y += wx * v.y; rs.z += wx * v.z; rs.w += wx * v.w;
      }
      rs.x *= wy; rs.y *= wy; rs.z *= wy; rs.w *= wy;
      *(float4*)&pooledP[yk][c4 * 4] = rs;
    }
  }
  __syncthreads();

  // --- reduce partials over Y ---------------------------------------------
  {
    const float inv_cnt = 1.0f / 256.0f;
    for (int c = tid; c < C_; c += 256) {
      float a = 0.f;
      for (int yk = 0; yk < ny; ++yk) a += pooledP[yk][c];
      pooled[c] = a * inv_cnt;
    }
  }
  __syncthreads();

  // --- Layer 1 (528 -> 128, relu): 2 half-K partials x 128 outputs --------
  {
    const int j = tid & 127;
    const int half = tid >> 7;
    const int cb = half * 264;
    float acc = 0.f;
    const float* w = W1 + j;
    #pragma unroll 4
    for (int c = cb; c < cb + 264; c += 4) {
      const float4 p = *(const float4*)&pooled[c];
      acc += p.x * w[(size_t)(c + 0) * 128];
      acc += p.y * w[(size_t)(c + 1) * 128];
      acc += p.z * w[(size_t)(c + 2) * 128];
      acc += p.w * w[(size_t)(c + 3) * 128];
    }
    h1p[half][j] = acc;
  }
  __syncthreads();
  if (tid < 128) h1[tid] = fmaxf(h1p[0][tid] + h1p[1][tid] + b1[tid], 0.f);
  __syncthreads();

  // --- Layer 2 (128 -> 32): 8 partials x 32 outputs -----------------------
  {
    const int j = tid & 31;
    const int part = tid >> 5;
    float acc = 0.f;
    #pragma unroll
    for (int k = part * 16; k < part * 16 + 16; ++k) {
      acc += h1[k] * W2[k * 32 + j];
    }
    p2[part][j] = acc;
  }
  __syncthreads();
  if (tid < 32) {
    float acc = b2[tid];
    #pragma unroll
    for (int p = 0; p < 8; ++p) acc += p2[p][tid];
    h2[tid] = acc;
  }
  __syncthreads();

  // --- Layer 3 (32 -> 1) + sigmoid, wave reduce ---------------------------
  if (tid < 64) {
    float t = (tid < 32) ? h2[tid] * W3[tid] : 0.f;
    #pragma unroll
    for (int off = 16; off >= 1; off >>= 1) t += __shfl_down(t, off);
    if (tid == 0) out[r] = 1.0f / (1.0f + expf(-(t + b3[0])));
  }
}

extern "C" void kernel_launch(void* const* d_in, const int* in_sizes, int n_in,
                              void* d_out, int out_size, void* d_ws, size_t ws_size,
                              hipStream_t stream) {
  const float* x    = (const float*)d_in[0];
  const float* bbox = (const float*)d_in[1];
  const float* W1   = (const float*)d_in[2];
  const float* b1   = (const float*)d_in[3];
  const float* W2   = (const float*)d_in[4];
  const float* b2   = (const float*)d_in[5];
  const float* W3   = (const float*)d_in[6];
  const float* b3   = (const float*)d_in[7];
  float* out = (float*)d_out;

  float* feat_t = (float*)d_ws;  // 8*1024*528 floats = 17.3 MB

  mean_transpose<<<dim3(16, 9, 8), 256, 0, stream>>>(x, feat_t);
  roi_mlp<<<R_, 256, 0, stream>>>(feat_t, bbox, W1, b1, W2, b2, W3, b3, out);
}